// Round 14
// baseline (881.391 us; speedup 1.0000x reference)
//
#include <hip/hip_runtime.h>
#include <cstdint>

#pragma STDC FP_CONTRACT OFF

// ---------------------------------------------------------------------------
// GridCLIP forward: hash-grid encode (16 levels x 8) -> MLP 128->256->256->1024
// Round 14: ONE fused MLP kernel (was gemm1 + fused23). Per 128-row stripe
// (512 thr, 8 waves, 144KB LDS, 1 block/CU):
//   ph1: gh tile staged once (32KB, swizzled gld16) @ W1-in-regs -> H1 (LDS)
//   ph2: H1 @ W2-in-regs -> H2 (LDS)
//   ph3: H2 @ W3 streamed 16-col chunks dbuf'd (2x8KB), chunks 0/1 issued in
//        the prologue (latency hidden under ph1/2)
// h1/h2 never touch HBM; gh read once. MFMA k-orders ascending, f32 accum
// identical to R13 -> bit-identical output (canary absmax 4.768372e-07).
// Encode unchanged (R8-proven XLA div->mul-reciprocal chain).
// ---------------------------------------------------------------------------

typedef _Float16 f16;
typedef __attribute__((ext_vector_type(8))) _Float16 f16x8;
typedef __attribute__((ext_vector_type(4))) float f32x4;

#define ACT_SCALE 4096.0f
#define INV_ACT_SCALE (1.0f / 4096.0f)

__device__ __forceinline__ void gld16(const void* g, void* l) {
  __builtin_amdgcn_global_load_lds(
      (const __attribute__((address_space(1))) void*)(uintptr_t)g,
      (__attribute__((address_space(3))) void*)(uint32_t)(uintptr_t)l,
      16, 0, 0);
}

// ---------------- grid encode (bit-exact XLA chain, f16-scaled output) -----
__global__ __launch_bounds__(256) void grid_encode_kernel(
    const float* __restrict__ x, const float* __restrict__ emb,
    f16* __restrict__ gh, int p0, int npts)
{
#pragma clang fp contract(off)
  int g = blockIdx.x * blockDim.x + threadIdx.x;
  if (g >= npts * 16) return;
  int pl = g >> 4;
  int l  = g & 15;
  int p  = p0 + pl;

  float x0 = x[3 * p + 0];
  float x1 = x[3 * p + 1];
  float x2 = x[3 * p + 2];

  float t0 = (x0 + 10.0f) * 0.05f;
  float t1 = (x1 + 10.0f) * 0.05f;
  float t2 = (x2 + 10.0f) * 0.05f;
  asm volatile("" : "+v"(t0), "+v"(t1), "+v"(t2));
  float u0 = (t0 + 1.0f) * 0.5f;
  float u1 = (t1 + 1.0f) * 0.5f;
  float u2 = (t2 + 1.0f) * 0.5f;
  asm volatile("" : "+v"(u0), "+v"(u1), "+v"(u2));

  float scale = (float)((16 << l) - 1);
  float pos0 = u0 * scale + 0.5f;
  float pos1 = u1 * scale + 0.5f;
  float pos2 = u2 * scale + 0.5f;

  float fb0 = floorf(pos0), fb1 = floorf(pos1), fb2 = floorf(pos2);
  float f0 = pos0 - fb0;
  float f1 = pos1 - fb1;
  float f2 = pos2 - fb2;
  uint32_t px = (uint32_t)fb0, py = (uint32_t)fb1, pz = (uint32_t)fb2;

  uint32_t mask = (l < 3) ? ((4096u << (3 * l)) - 1u) : 2097151u;
  uint32_t off;
  if (l == 0)      off = 0u;
  else if (l == 1) off = 4096u;
  else if (l == 2) off = 36864u;
  else             off = 299008u + (uint32_t)(l - 3) * 2097152u;

  float wx[2] = {1.0f - f0, f0};
  float wy[2] = {1.0f - f1, f1};
  float wz[2] = {1.0f - f2, f2};

  float acc[8];
#pragma unroll
  for (int j = 0; j < 8; ++j) acc[j] = 0.0f;

#pragma unroll
  for (int c = 0; c < 8; ++c) {
    uint32_t cx = px + (uint32_t)(c & 1);
    uint32_t cy = py + (uint32_t)((c >> 1) & 1);
    uint32_t cz = pz + (uint32_t)((c >> 2) & 1);
    float w = wx[c & 1] * wy[(c >> 1) & 1] * wz[(c >> 2) & 1];
    uint32_t h = cx ^ (cy * 2654435761u) ^ (cz * 805459861u);
    uint32_t idx = (h & mask) + off;
    const float4* e = (const float4*)(emb + (size_t)idx * 8);
    float4 e0 = e[0];
    float4 e1 = e[1];
    float m0 = w * e0.x, m1 = w * e0.y, m2 = w * e0.z, m3 = w * e0.w;
    float m4 = w * e1.x, m5 = w * e1.y, m6 = w * e1.z, m7 = w * e1.w;
    asm volatile("" : "+v"(m0), "+v"(m1), "+v"(m2), "+v"(m3),
                      "+v"(m4), "+v"(m5), "+v"(m6), "+v"(m7));
    acc[0] += m0; acc[1] += m1; acc[2] += m2; acc[3] += m3;
    acc[4] += m4; acc[5] += m5; acc[6] += m6; acc[7] += m7;
  }

  f16x8 o;
#pragma unroll
  for (int j = 0; j < 8; ++j) o[j] = (f16)(acc[j] * ACT_SCALE);
  *(f16x8*)&gh[(size_t)pl * 128 + l * 8] = o;
}

// ---------------- weight preps ---------------------------------------------
// W3 -> f16 transposed [N][K]
template <int K, int N>
__global__ __launch_bounds__(256) void prep_w(
    const float* __restrict__ W, f16* __restrict__ Wt)
{
  int i = blockIdx.x * 256 + threadIdx.x;
  if (i >= N * K) return;
  int n = i / K, k = i - n * K;
  Wt[i] = (f16)W[(size_t)k * N + n];
}

// W1 (128x256) -> frag-ordered: idx = ((q*16+kg)*16+lr)*8+e, q=n>>4, kg=k>>3
__global__ __launch_bounds__(256) void prep_w1f(
    const float* __restrict__ W1, f16* __restrict__ Wf1)
{
  int i = blockIdx.x * 256 + threadIdx.x;  // 0..32767
  if (i >= 128 * 256) return;
  int e  = i & 7;
  int lr = (i >> 3) & 15;
  int kg = (i >> 7) & 15;
  int q  = i >> 11;
  int n = q * 16 + lr;
  int k = kg * 8 + e;
  Wf1[i] = (f16)W1[(size_t)k * 256 + n];
}

// W2 (256x256) -> frag-ordered: idx = ((q*32+kg)*16+lr)*8+e
__global__ __launch_bounds__(256) void prep_w2f(
    const float* __restrict__ W2, f16* __restrict__ Wf2)
{
  int i = blockIdx.x * 256 + threadIdx.x;  // 0..65535
  if (i >= 256 * 256) return;
  int e  = i & 7;
  int lr = (i >> 3) & 15;
  int kg = (i >> 7) & 31;
  int q  = i >> 12;
  int n = q * 16 + lr;
  int k = kg * 8 + e;
  Wf2[i] = (f16)W2[(size_t)k * 256 + n];
}

// ---------------- fused MLP (gemm1+2+3, one kernel) ------------------------
__global__ __launch_bounds__(512) void fused_mlp(
    const f16* __restrict__ gh, const f16* __restrict__ Wf1,
    const float* __restrict__ b1, const f16* __restrict__ Wf2,
    const float* __restrict__ b2, const f16* __restrict__ Wt3,
    const float* __restrict__ b3, float* __restrict__ out,
    int rowBase, int nTotal)
{
  __shared__ alignas(16) f16 As2[2][4096];   // 2 x 8KB W3 chunk dbuf
  __shared__ alignas(16) f16 H1[128 * 256];  // 64KB swizzled h1
  __shared__ alignas(16) f16 H2[128 * 256];  // 64KB swizzled h2 (gh in 1st 32KB during ph1)

  const int tid  = threadIdx.x;
  const int lane = tid & 63;
  const int wid  = tid >> 6;      // 0..7
  const int bm   = blockIdx.x * 128;
  const int lr   = lane & 15;
  const int lkg  = lane >> 4;     // 0..3

  // W3 16-col chunk staging: 512 granules, 1/thread, linear dest,
  // inverse-swizzled source (rule 21)
  auto stage3 = [&](int buf, int c) {
    const int g   = tid;
    const int row = g >> 5;                       // col-in-chunk 0..15
    const int sg  = g & 31;
    const int gs  = (sg & 24) | ((sg ^ row) & 7);
    gld16(&Wt3[(size_t)(c * 16 + row) * 256 + gs * 8], &As2[buf][g * 8]);
  };

  // ---- prologue: stage gh tile (32KB into H2, 16-granule rows, row-swizzle)
  //      + first two W3 chunks (latency hidden under ph1/ph2)
#pragma unroll
  for (int s = 0; s < 4; ++s) {
    const int g   = tid + s * 512;               // 2048 granules
    const int row = g >> 4;
    const int sg  = g & 15;
    const int gs  = (sg & 8) | ((sg ^ row) & 7);
    gld16(&gh[(size_t)(bm + row) * 128 + gs * 8], &H2[g * 8]);
  }
  stage3(0, 0);
  stage3(1, 1);
  __syncthreads();

  // ===== phase 1: h1 = relu(gh @ W1 + b1*S) =====
  {
    const int rowg = wid >> 2, colg = wid & 3;
    f16x8 bf1[4][4];
#pragma unroll
    for (int j = 0; j < 4; ++j)
#pragma unroll
      for (int f = 0; f < 4; ++f)
        bf1[j][f] = *(const f16x8*)&Wf1[(((colg * 4 + j) * 16 + f * 4 + lkg) * 16 + lr) * 8];

    f32x4 acc[4][4];
#pragma unroll
    for (int i = 0; i < 4; ++i)
#pragma unroll
      for (int j = 0; j < 4; ++j) acc[i][j] = (f32x4){0.f, 0.f, 0.f, 0.f};

#pragma unroll
    for (int f = 0; f < 4; ++f) {
      f16x8 af[4];
#pragma unroll
      for (int i = 0; i < 4; ++i) {
        const int r  = rowg * 64 + i * 16 + lr;
        const int kg = f * 4 + lkg;
        const int gs = (kg & 8) | ((kg ^ r) & 7);
        af[i] = *(const f16x8*)&H2[r * 128 + gs * 8];
      }
#pragma unroll
      for (int i = 0; i < 4; ++i)
#pragma unroll
        for (int j = 0; j < 4; ++j)
          acc[i][j] = __builtin_amdgcn_mfma_f32_16x16x32_f16(
              af[i], bf1[j][f], acc[i][j], 0, 0, 0);
    }

    // h1 -> H1 swizzled (slot = (kg&24)|((kg^row)&7))
#pragma unroll
    for (int i = 0; i < 4; ++i)
#pragma unroll
      for (int j = 0; j < 4; ++j) {
        const int col = colg * 64 + j * 16 + lr;
        const float bv = b1[col];
        const int kg = col >> 3, e = col & 7;
#pragma unroll
        for (int q = 0; q < 4; ++q) {
          const int row = rowg * 64 + i * 16 + lkg * 4 + q;
          const int kgs = (kg & 24) | ((kg ^ row) & 7);
          float v = fmaxf(acc[i][j][q] + bv * ACT_SCALE, 0.0f);
          H1[row * 256 + kgs * 8 + e] = (f16)v;
        }
      }
  }
  __syncthreads();  // H1 visible; all gh reads (H2) complete

  // ===== phase 2: h2 = relu(h1 @ W2 + b2*S) =====
  {
    const int rowg = wid >> 2, colg = wid & 3;
    f16x8 bf2[4][8];
#pragma unroll
    for (int j = 0; j < 4; ++j)
#pragma unroll
      for (int f = 0; f < 8; ++f)
        bf2[j][f] = *(const f16x8*)&Wf2[(((colg * 4 + j) * 32 + f * 4 + lkg) * 16 + lr) * 8];

    f32x4 acc[4][4];
#pragma unroll
    for (int i = 0; i < 4; ++i)
#pragma unroll
      for (int j = 0; j < 4; ++j) acc[i][j] = (f32x4){0.f, 0.f, 0.f, 0.f};

#pragma unroll
    for (int f = 0; f < 8; ++f) {
      f16x8 af[4];
#pragma unroll
      for (int i = 0; i < 4; ++i) {
        const int r   = rowg * 64 + i * 16 + lr;
        const int kg  = f * 4 + lkg;
        const int kgs = (kg & 24) | ((kg ^ r) & 7);
        af[i] = *(const f16x8*)&H1[r * 256 + kgs * 8];
      }
#pragma unroll
      for (int i = 0; i < 4; ++i)
#pragma unroll
        for (int j = 0; j < 4; ++j)
          acc[i][j] = __builtin_amdgcn_mfma_f32_16x16x32_f16(
              af[i], bf2[j][f], acc[i][j], 0, 0, 0);
    }

    // h2 -> H2 swizzled (overwrites gh region; all gh reads done at barrier)
#pragma unroll
    for (int i = 0; i < 4; ++i)
#pragma unroll
      for (int j = 0; j < 4; ++j) {
        const int col = colg * 64 + j * 16 + lr;
        const float bv = b2[col];
        const int kg = col >> 3, e = col & 7;
#pragma unroll
        for (int q = 0; q < 4; ++q) {
          const int row = rowg * 64 + i * 16 + lkg * 4 + q;
          const int kgs = (kg & 24) | ((kg ^ row) & 7);
          float v = fmaxf(acc[i][j][q] + bv * ACT_SCALE, 0.0f);
          H2[row * 256 + kgs * 8 + e] = (f16)v;
        }
      }
  }
  __syncthreads();  // H2 visible; W3 chunks 0/1 drained (vmcnt in barrier)

  // ===== phase 3: out = h2 @ W3 + b3, 64 chunks of 16 cols =====
  f16x8 af3[8];
#pragma unroll
  for (int f = 0; f < 8; ++f) {
    const int r   = wid * 16 + lr;
    const int kg  = f * 4 + lkg;
    const int kgs = (kg & 24) | ((kg ^ r) & 7);
    af3[f] = *(const f16x8*)&H2[r * 256 + kgs * 8];
  }

  for (int c = 0; c < 64; ++c) {
    const int buf = c & 1;
    f16x8 bf3[8];
#pragma unroll
    for (int f = 0; f < 8; ++f) {
      const int kg  = f * 4 + lkg;
      const int kgs = (kg & 24) | ((kg ^ lr) & 7);
      bf3[f] = *(const f16x8*)&As2[buf][(lr * 32 + kgs) * 8];
    }
    f32x4 a = (f32x4){0.f, 0.f, 0.f, 0.f};
#pragma unroll
    for (int f = 0; f < 8; ++f)
      a = __builtin_amdgcn_mfma_f32_16x16x32_f16(af3[f], bf3[f], a, 0, 0, 0);

    const int col = c * 16 + lr;
    const float bv = b3[col];
#pragma unroll
    for (int q = 0; q < 4; ++q) {
      const int row = bm + wid * 16 + lkg * 4 + q;
      float v = a[q] * INV_ACT_SCALE + bv;
      size_t grow = (size_t)(rowBase + row);
      float* dst = (col < 512)
                       ? (out + grow * 512 + col)
                       : (out + (size_t)nTotal * 512 + grow * 512 + (col - 512));
      *dst = v;
    }
    __syncthreads();                    // As2[buf] reads done; c+1 staged
    if (c + 2 < 64) stage3(buf, c + 2); // async refill
  }
}

// ---------------- launch ----------------
extern "C" void kernel_launch(void* const* d_in, const int* in_sizes, int n_in,
                              void* d_out, int out_size, void* d_ws, size_t ws_size,
                              hipStream_t stream)
{
  const float* x   = (const float*)d_in[0];
  const float* emb = (const float*)d_in[1];
  const float* W1  = (const float*)d_in[2];
  const float* b1  = (const float*)d_in[3];
  const float* W2  = (const float*)d_in[4];
  const float* b2  = (const float*)d_in[5];
  const float* W3  = (const float*)d_in[6];
  const float* b3  = (const float*)d_in[7];
  float* out = (float*)d_out;

  const int NPTS = in_sizes[0] / 3;  // 262144

  // ws layout: Wf1 | Wf2 | Wt3 | gh(f16)
  f16* Wf1 = (f16*)d_ws;                 // 128*256 frag-ordered
  f16* Wf2 = Wf1 + 128 * 256;            // 256*256 frag-ordered
  f16* Wt3 = Wf2 + 256 * 256;            // 256*1024 transposed [N][K]
  f16* gh0 = Wt3 + 256 * 1024;
  const size_t wtBytes = (size_t)(128 * 256 + 256 * 256 + 256 * 1024) * sizeof(f16);

  // chunk rows: gh C*128 f16 = 256 B/row
  long long cmax = (long long)((ws_size - wtBytes) / 256);
  int C = (int)((cmax / 128) * 128);
  if (C > NPTS) C = NPTS;
  if (C < 128) C = 128;

  prep_w1f<<<(128 * 256 + 255) / 256, 256, 0, stream>>>(W1, Wf1);
  prep_w2f<<<(256 * 256 + 255) / 256, 256, 0, stream>>>(W2, Wf2);
  prep_w<256, 1024><<<(256 * 1024 + 255) / 256, 256, 0, stream>>>(W3, Wt3);

  for (int p0 = 0; p0 < NPTS; p0 += C) {
    int cur = (NPTS - p0 < C) ? (NPTS - p0) : C;

    int nthr = cur * 16;
    grid_encode_kernel<<<(nthr + 255) / 256, 256, 0, stream>>>(x, emb, gh0, p0, cur);

    fused_mlp<<<cur / 128, 512, 0, stream>>>(gh0, Wf1, b1, Wf2, b2, Wt3, b3,
                                             out, p0, NPTS);
  }
}

// Round 15
// 833.607 us; speedup vs baseline: 1.0573x; 1.0573x over previous
//
#include <hip/hip_runtime.h>
#include <cstdint>

#pragma STDC FP_CONTRACT OFF

// ---------------------------------------------------------------------------
// GridCLIP forward: hash-grid encode (16 levels x 8) -> MLP 128->256->256->1024
// Round 15: phase 3 rebuilt with T4 discipline: raw s_barrier + counted
// s_waitcnt vmcnt(N) (never 0), 3-deep W3 chunk ring (3x8KB), stores never
// drained in-loop. Accounting per wave per iter: 1 gld16 + 4 stores ->
// steady wait vmcnt(9) retires the 2-iter-old chunk loads only. b3 cached in
// LDS (a global load in the body would break the vmcnt count). sched_barrier
// fences after inline-asm waits (rule 18). Phases 1-2 / encode unchanged ->
// bit-identical output (canary absmax 4.768372e-07).
// ---------------------------------------------------------------------------

typedef _Float16 f16;
typedef __attribute__((ext_vector_type(8))) _Float16 f16x8;
typedef __attribute__((ext_vector_type(4))) float f32x4;

#define ACT_SCALE 4096.0f
#define INV_ACT_SCALE (1.0f / 4096.0f)

__device__ __forceinline__ void gld16(const void* g, void* l) {
  __builtin_amdgcn_global_load_lds(
      (const __attribute__((address_space(1))) void*)(uintptr_t)g,
      (__attribute__((address_space(3))) void*)(uint32_t)(uintptr_t)l,
      16, 0, 0);
}

// ---------------- grid encode (bit-exact XLA chain, f16-scaled output) -----
__global__ __launch_bounds__(256) void grid_encode_kernel(
    const float* __restrict__ x, const float* __restrict__ emb,
    f16* __restrict__ gh, int p0, int npts)
{
#pragma clang fp contract(off)
  int g = blockIdx.x * blockDim.x + threadIdx.x;
  if (g >= npts * 16) return;
  int pl = g >> 4;
  int l  = g & 15;
  int p  = p0 + pl;

  float x0 = x[3 * p + 0];
  float x1 = x[3 * p + 1];
  float x2 = x[3 * p + 2];

  float t0 = (x0 + 10.0f) * 0.05f;
  float t1 = (x1 + 10.0f) * 0.05f;
  float t2 = (x2 + 10.0f) * 0.05f;
  asm volatile("" : "+v"(t0), "+v"(t1), "+v"(t2));
  float u0 = (t0 + 1.0f) * 0.5f;
  float u1 = (t1 + 1.0f) * 0.5f;
  float u2 = (t2 + 1.0f) * 0.5f;
  asm volatile("" : "+v"(u0), "+v"(u1), "+v"(u2));

  float scale = (float)((16 << l) - 1);
  float pos0 = u0 * scale + 0.5f;
  float pos1 = u1 * scale + 0.5f;
  float pos2 = u2 * scale + 0.5f;

  float fb0 = floorf(pos0), fb1 = floorf(pos1), fb2 = floorf(pos2);
  float f0 = pos0 - fb0;
  float f1 = pos1 - fb1;
  float f2 = pos2 - fb2;
  uint32_t px = (uint32_t)fb0, py = (uint32_t)fb1, pz = (uint32_t)fb2;

  uint32_t mask = (l < 3) ? ((4096u << (3 * l)) - 1u) : 2097151u;
  uint32_t off;
  if (l == 0)      off = 0u;
  else if (l == 1) off = 4096u;
  else if (l == 2) off = 36864u;
  else             off = 299008u + (uint32_t)(l - 3) * 2097152u;

  float wx[2] = {1.0f - f0, f0};
  float wy[2] = {1.0f - f1, f1};
  float wz[2] = {1.0f - f2, f2};

  float acc[8];
#pragma unroll
  for (int j = 0; j < 8; ++j) acc[j] = 0.0f;

#pragma unroll
  for (int c = 0; c < 8; ++c) {
    uint32_t cx = px + (uint32_t)(c & 1);
    uint32_t cy = py + (uint32_t)((c >> 1) & 1);
    uint32_t cz = pz + (uint32_t)((c >> 2) & 1);
    float w = wx[c & 1] * wy[(c >> 1) & 1] * wz[(c >> 2) & 1];
    uint32_t h = cx ^ (cy * 2654435761u) ^ (cz * 805459861u);
    uint32_t idx = (h & mask) + off;
    const float4* e = (const float4*)(emb + (size_t)idx * 8);
    float4 e0 = e[0];
    float4 e1 = e[1];
    float m0 = w * e0.x, m1 = w * e0.y, m2 = w * e0.z, m3 = w * e0.w;
    float m4 = w * e1.x, m5 = w * e1.y, m6 = w * e1.z, m7 = w * e1.w;
    asm volatile("" : "+v"(m0), "+v"(m1), "+v"(m2), "+v"(m3),
                      "+v"(m4), "+v"(m5), "+v"(m6), "+v"(m7));
    acc[0] += m0; acc[1] += m1; acc[2] += m2; acc[3] += m3;
    acc[4] += m4; acc[5] += m5; acc[6] += m6; acc[7] += m7;
  }

  f16x8 o;
#pragma unroll
  for (int j = 0; j < 8; ++j) o[j] = (f16)(acc[j] * ACT_SCALE);
  *(f16x8*)&gh[(size_t)pl * 128 + l * 8] = o;
}

// ---------------- weight preps ---------------------------------------------
template <int K, int N>
__global__ __launch_bounds__(256) void prep_w(
    const float* __restrict__ W, f16* __restrict__ Wt)
{
  int i = blockIdx.x * 256 + threadIdx.x;
  if (i >= N * K) return;
  int n = i / K, k = i - n * K;
  Wt[i] = (f16)W[(size_t)k * N + n];
}

__global__ __launch_bounds__(256) void prep_w1f(
    const float* __restrict__ W1, f16* __restrict__ Wf1)
{
  int i = blockIdx.x * 256 + threadIdx.x;
  if (i >= 128 * 256) return;
  int e  = i & 7;
  int lr = (i >> 3) & 15;
  int kg = (i >> 7) & 15;
  int q  = i >> 11;
  int n = q * 16 + lr;
  int k = kg * 8 + e;
  Wf1[i] = (f16)W1[(size_t)k * 256 + n];
}

__global__ __launch_bounds__(256) void prep_w2f(
    const float* __restrict__ W2, f16* __restrict__ Wf2)
{
  int i = blockIdx.x * 256 + threadIdx.x;
  if (i >= 256 * 256) return;
  int e  = i & 7;
  int lr = (i >> 3) & 15;
  int kg = (i >> 7) & 31;
  int q  = i >> 12;
  int n = q * 16 + lr;
  int k = kg * 8 + e;
  Wf2[i] = (f16)W2[(size_t)k * 256 + n];
}

// ---------------- fused MLP ------------------------------------------------
__global__ __launch_bounds__(512) void fused_mlp(
    const f16* __restrict__ gh, const f16* __restrict__ Wf1,
    const float* __restrict__ b1, const f16* __restrict__ Wf2,
    const float* __restrict__ b2, const f16* __restrict__ Wt3,
    const float* __restrict__ b3, float* __restrict__ out,
    int rowBase, int nTotal)
{
  __shared__ alignas(16) f16 As2[3][4096];   // 3 x 8KB W3 chunk ring
  __shared__ alignas(16) f16 H1[128 * 256];  // 64KB swizzled h1
  __shared__ alignas(16) f16 H2[128 * 256];  // 64KB swizzled h2 (gh during ph1)
  __shared__ float B3s[1024];                // 4KB b3 cache

  const int tid  = threadIdx.x;
  const int lane = tid & 63;
  const int wid  = tid >> 6;      // 0..7
  const int bm   = blockIdx.x * 128;
  const int lr   = lane & 15;
  const int lkg  = lane >> 4;     // 0..3

  // W3 16-col chunk staging: 512 granules, 1 gld16/thread (1 per wave)
  auto stage3 = [&](int buf, int c) {
    const int g   = tid;
    const int row = g >> 5;                       // col-in-chunk 0..15
    const int sg  = g & 31;
    const int gs  = (sg & 24) | ((sg ^ row) & 7);
    gld16(&Wt3[(size_t)(c * 16 + row) * 256 + gs * 8], &As2[buf][g * 8]);
  };

  // ---- prologue: gh tile (32KB into H2) + W3 chunks 0..2 + b3 cache
#pragma unroll
  for (int s = 0; s < 4; ++s) {
    const int g   = tid + s * 512;               // 2048 granules
    const int row = g >> 4;
    const int sg  = g & 15;
    const int gs  = (sg & 8) | ((sg ^ row) & 7);
    gld16(&gh[(size_t)(bm + row) * 128 + gs * 8], &H2[g * 8]);
  }
  stage3(0, 0);
  stage3(1, 1);
  stage3(2, 2);
  B3s[tid] = b3[tid];
  B3s[tid + 512] = b3[tid + 512];
  __syncthreads();

  // ===== phase 1: h1 = relu(gh @ W1 + b1*S) =====
  {
    const int rowg = wid >> 2, colg = wid & 3;
    f16x8 bf1[4][4];
#pragma unroll
    for (int j = 0; j < 4; ++j)
#pragma unroll
      for (int f = 0; f < 4; ++f)
        bf1[j][f] = *(const f16x8*)&Wf1[(((colg * 4 + j) * 16 + f * 4 + lkg) * 16 + lr) * 8];

    f32x4 acc[4][4];
#pragma unroll
    for (int i = 0; i < 4; ++i)
#pragma unroll
      for (int j = 0; j < 4; ++j) acc[i][j] = (f32x4){0.f, 0.f, 0.f, 0.f};

#pragma unroll
    for (int f = 0; f < 4; ++f) {
      f16x8 af[4];
#pragma unroll
      for (int i = 0; i < 4; ++i) {
        const int r  = rowg * 64 + i * 16 + lr;
        const int kg = f * 4 + lkg;
        const int gs = (kg & 8) | ((kg ^ r) & 7);
        af[i] = *(const f16x8*)&H2[r * 128 + gs * 8];
      }
#pragma unroll
      for (int i = 0; i < 4; ++i)
#pragma unroll
        for (int j = 0; j < 4; ++j)
          acc[i][j] = __builtin_amdgcn_mfma_f32_16x16x32_f16(
              af[i], bf1[j][f], acc[i][j], 0, 0, 0);
    }

#pragma unroll
    for (int i = 0; i < 4; ++i)
#pragma unroll
      for (int j = 0; j < 4; ++j) {
        const int col = colg * 64 + j * 16 + lr;
        const float bv = b1[col];
        const int kg = col >> 3, e = col & 7;
#pragma unroll
        for (int q = 0; q < 4; ++q) {
          const int row = rowg * 64 + i * 16 + lkg * 4 + q;
          const int kgs = (kg & 24) | ((kg ^ row) & 7);
          float v = fmaxf(acc[i][j][q] + bv * ACT_SCALE, 0.0f);
          H1[row * 256 + kgs * 8 + e] = (f16)v;
        }
      }
  }
  __syncthreads();

  // ===== phase 2: h2 = relu(h1 @ W2 + b2*S) =====
  {
    const int rowg = wid >> 2, colg = wid & 3;
    f16x8 bf2[4][8];
#pragma unroll
    for (int j = 0; j < 4; ++j)
#pragma unroll
      for (int f = 0; f < 8; ++f)
        bf2[j][f] = *(const f16x8*)&Wf2[(((colg * 4 + j) * 32 + f * 4 + lkg) * 16 + lr) * 8];

    f32x4 acc[4][4];
#pragma unroll
    for (int i = 0; i < 4; ++i)
#pragma unroll
      for (int j = 0; j < 4; ++j) acc[i][j] = (f32x4){0.f, 0.f, 0.f, 0.f};

#pragma unroll
    for (int f = 0; f < 8; ++f) {
      f16x8 af[4];
#pragma unroll
      for (int i = 0; i < 4; ++i) {
        const int r   = rowg * 64 + i * 16 + lr;
        const int kg  = f * 4 + lkg;
        const int kgs = (kg & 24) | ((kg ^ r) & 7);
        af[i] = *(const f16x8*)&H1[r * 256 + kgs * 8];
      }
#pragma unroll
      for (int i = 0; i < 4; ++i)
#pragma unroll
        for (int j = 0; j < 4; ++j)
          acc[i][j] = __builtin_amdgcn_mfma_f32_16x16x32_f16(
              af[i], bf2[j][f], acc[i][j], 0, 0, 0);
    }

#pragma unroll
    for (int i = 0; i < 4; ++i)
#pragma unroll
      for (int j = 0; j < 4; ++j) {
        const int col = colg * 64 + j * 16 + lr;
        const float bv = b2[col];
        const int kg = col >> 3, e = col & 7;
#pragma unroll
        for (int q = 0; q < 4; ++q) {
          const int row = rowg * 64 + i * 16 + lkg * 4 + q;
          const int kgs = (kg & 24) | ((kg ^ row) & 7);
          float v = fmaxf(acc[i][j][q] + bv * ACT_SCALE, 0.0f);
          H2[row * 256 + kgs * 8 + e] = (f16)v;
        }
      }
  }
  __syncthreads();  // H2 visible; all prologue loads long drained

  // ===== phase 3: out = h2 @ W3 + b3 — counted-vmcnt streaming =====
  // Per wave per iter: 1 gld16 (stage) + 4 global stores. 3-chunk ring.
  // Steady wait vmcnt(9): retires the loads staged 2 iterations ago only;
  // stores stay in flight. Barrier (raw) certifies cross-wave staging of
  // chunk c+1 and completion of all reads of chunk c before its restage.
  f16x8 af3[8];
#pragma unroll
  for (int f = 0; f < 8; ++f) {
    const int r   = wid * 16 + lr;
    const int kg  = f * 4 + lkg;
    const int kgs = (kg & 24) | ((kg ^ r) & 7);
    af3[f] = *(const f16x8*)&H2[r * 256 + kgs * 8];
  }

  auto body3 = [&](int c, int wmode, bool dostage) {
    if (wmode == 9) {
      asm volatile("s_waitcnt vmcnt(9)" ::: "memory");
      __builtin_amdgcn_sched_barrier(0);
    } else if (wmode == 8) {
      asm volatile("s_waitcnt vmcnt(8)" ::: "memory");
      __builtin_amdgcn_sched_barrier(0);
    }
    const int buf = c % 3;
    f16x8 bf3[8];
#pragma unroll
    for (int f = 0; f < 8; ++f) {
      const int kg  = f * 4 + lkg;
      const int kgs = (kg & 24) | ((kg ^ lr) & 7);
      bf3[f] = *(const f16x8*)&As2[buf][(lr * 32 + kgs) * 8];
    }
    const int col = c * 16 + lr;
    const float bv = B3s[col];
    asm volatile("s_waitcnt lgkmcnt(0)" ::: "memory");
    __builtin_amdgcn_sched_barrier(0);
    __builtin_amdgcn_s_barrier();             // raw: no vmcnt drain
    __builtin_amdgcn_sched_barrier(0);
    if (dostage) stage3(buf, c + 3);
    f32x4 a = (f32x4){0.f, 0.f, 0.f, 0.f};
#pragma unroll
    for (int f = 0; f < 8; ++f)
      a = __builtin_amdgcn_mfma_f32_16x16x32_f16(af3[f], bf3[f], a, 0, 0, 0);
#pragma unroll
    for (int q = 0; q < 4; ++q) {
      const int row = bm + wid * 16 + lkg * 4 + q;
      float v = a[q] * INV_ACT_SCALE + bv;
      size_t grow = (size_t)(rowBase + row);
      float* dst = (col < 512)
                       ? (out + grow * 512 + col)
                       : (out + (size_t)nTotal * 512 + grow * 512 + (col - 512));
      *dst = v;
    }
  };

  body3(0, 0, true);
  body3(1, 0, true);
  for (int c = 2; c <= 60; ++c) body3(c, 9, true);
  body3(61, 9, false);
  body3(62, 8, false);
  body3(63, 0, false);
}

// ---------------- launch ----------------
extern "C" void kernel_launch(void* const* d_in, const int* in_sizes, int n_in,
                              void* d_out, int out_size, void* d_ws, size_t ws_size,
                              hipStream_t stream)
{
  const float* x   = (const float*)d_in[0];
  const float* emb = (const float*)d_in[1];
  const float* W1  = (const float*)d_in[2];
  const float* b1  = (const float*)d_in[3];
  const float* W2  = (const float*)d_in[4];
  const float* b2  = (const float*)d_in[5];
  const float* W3  = (const float*)d_in[6];
  const float* b3  = (const float*)d_in[7];
  float* out = (float*)d_out;

  const int NPTS = in_sizes[0] / 3;  // 262144

  // ws layout: Wf1 | Wf2 | Wt3 | gh(f16)
  f16* Wf1 = (f16*)d_ws;                 // 128*256 frag-ordered
  f16* Wf2 = Wf1 + 128 * 256;            // 256*256 frag-ordered
  f16* Wt3 = Wf2 + 256 * 256;            // 256*1024 transposed [N][K]
  f16* gh0 = Wt3 + 256 * 1024;
  const size_t wtBytes = (size_t)(128 * 256 + 256 * 256 + 256 * 1024) * sizeof(f16);

  long long cmax = (long long)((ws_size - wtBytes) / 256);
  int C = (int)((cmax / 128) * 128);
  if (C > NPTS) C = NPTS;
  if (C < 128) C = 128;

  prep_w1f<<<(128 * 256 + 255) / 256, 256, 0, stream>>>(W1, Wf1);
  prep_w2f<<<(256 * 256 + 255) / 256, 256, 0, stream>>>(W2, Wf2);
  prep_w<256, 1024><<<(256 * 1024 + 255) / 256, 256, 0, stream>>>(W3, Wt3);

  for (int p0 = 0; p0 < NPTS; p0 += C) {
    int cur = (NPTS - p0 < C) ? (NPTS - p0) : C;

    int nthr = cur * 16;
    grid_encode_kernel<<<(nthr + 255) / 256, 256, 0, stream>>>(x, emb, gh0, p0, cur);

    fused_mlp<<<cur / 128, 512, 0, stream>>>(gh0, Wf1, b1, Wf2, b2, Wt3, b3,
                                             out, p0, NPTS);
  }
}